// Round 15
// baseline (246.790 us; speedup 1.0000x reference)
//
#include <hip/hip_runtime.h>
#include <hip/hip_bf16.h>
#include <stdint.h>

#define HIDDEN  1024
#define FFN_DIM 2048
#define NEXP    8
#define NTOK    2048          // B*S
#define MAXROWS 5120          // sum of 128-padded per-expert counts <= 4096 + 8*127

typedef short bf16x8 __attribute__((ext_vector_type(8)));
typedef float f32x4  __attribute__((ext_vector_type(4)));

// ---------------- ws layout (bytes) ----------------
static const size_t OFF_CNT  = 0;                         // 8 ints
static const size_t OFF_BASE = 64;                        // 9 ints
static const size_t OFF_TOK  = 128;                       // 8*2048 ints
static const size_t OFF_WGT  = OFF_TOK + (size_t)NEXP*NTOK*4;
static const size_t OFF_XBF  = 131328;                    // 256-aligned
static const size_t XBF_B    = (size_t)NTOK*HIDDEN*2;
static const size_t OFF_W1S  = OFF_XBF + XBF_B;
static const size_t W_B      = (size_t)NEXP*FFN_DIM*HIDDEN*2;
static const size_t OFF_W3S  = OFF_W1S + W_B;
static const size_t OFF_W2S  = OFF_W3S + W_B;
static const size_t OFF_H    = OFF_W2S + W_B;
static const size_t H_B      = (size_t)MAXROWS*FFN_DIM*2;
static const size_t WS_NEED  = OFF_H + H_B;               // ~120 MB

__device__ __forceinline__ unsigned short f2bf(float f) {
  union { float f; unsigned u; } a; a.f = f;
  unsigned r = a.u + 0x7fff + ((a.u >> 16) & 1);          // RTN-even
  return (unsigned short)(r >> 16);
}

__device__ __forceinline__ void ld_g2l16(const void* gsrc, void* ldst) {
  __builtin_amdgcn_global_load_lds(
      (const __attribute__((address_space(1))) unsigned int*)gsrc,
      (__attribute__((address_space(3))) unsigned int*)ldst, 16, 0, 0);
}

// ---------------- Router: fp32-exact logits, top-2, renorm weights, bins; fused x->bf16 --------
__global__ __launch_bounds__(256) void router_kernel(
    const float* __restrict__ x, const float* __restrict__ gw,
    float* __restrict__ logits, int* __restrict__ cnt,
    int* __restrict__ tok, float* __restrict__ wgt,
    unsigned short* __restrict__ xbf)
{
  const int t   = blockIdx.x;
  const int tid = threadIdx.x;
  float4 xv = ((const float4*)(x + (size_t)t * HIDDEN))[tid];
  if (xbf) {
    ushort4 o;
    o.x = f2bf(xv.x); o.y = f2bf(xv.y); o.z = f2bf(xv.z); o.w = f2bf(xv.w);
    ((ushort4*)(xbf + (size_t)t * HIDDEN))[tid] = o;
  }
  float p[NEXP];
#pragma unroll
  for (int e = 0; e < NEXP; ++e) {
    float4 gv = ((const float4*)(gw + (size_t)e * HIDDEN))[tid];
    p[e] = xv.x * gv.x + xv.y * gv.y + xv.z * gv.z + xv.w * gv.w;
  }
#pragma unroll
  for (int e = 0; e < NEXP; ++e) {
#pragma unroll
    for (int off = 32; off > 0; off >>= 1)
      p[e] += __shfl_down(p[e], off, 64);
  }
  __shared__ float red[4][NEXP];
  const int wv = tid >> 6, ln = tid & 63;
  if (ln == 0) {
#pragma unroll
    for (int e = 0; e < NEXP; ++e) red[wv][e] = p[e];
  }
  __syncthreads();
  if (tid == 0) {
    float l[NEXP];
#pragma unroll
    for (int e = 0; e < NEXP; ++e) {
      l[e] = red[0][e] + red[1][e] + red[2][e] + red[3][e];
      logits[(size_t)t * NEXP + e] = l[e];
    }
    int i0 = 0;
#pragma unroll
    for (int e = 1; e < NEXP; ++e) if (l[e] > l[i0]) i0 = e;
    int i1 = (i0 == 0) ? 1 : 0;
#pragma unroll
    for (int e = 0; e < NEXP; ++e) if (e != i0 && l[e] > l[i1]) i1 = e;
    float w0 = 1.f / (1.f + expf(l[i1] - l[i0]));
    float w1 = 1.f - w0;
    int s0 = atomicAdd(&cnt[i0], 1);
    tok[i0 * NTOK + s0] = t;  wgt[i0 * NTOK + s0] = w0;
    int s1 = atomicAdd(&cnt[i1], 1);
    tok[i1 * NTOK + s1] = t;  wgt[i1 * NTOK + s1] = w1;
  }
}

// ---------------- 128-padded per-expert row bases ----------------
__global__ void prefix_kernel(const int* __restrict__ cnt, int* __restrict__ base) {
  if (threadIdx.x == 0 && blockIdx.x == 0) {
    int b = 0;
#pragma unroll
    for (int e = 0; e < NEXP; ++e) { base[e] = b; b += ((cnt[e] + 127) >> 7) << 7; }
    base[NEXP] = b;
  }
}

// ---------------- weight cvt + fragment shuffle (coalesced reads, LDS-staged) ------------------
// Unit = (tensor, 16-row panel, 128-col chunk). Reads are fully coalesced fp32 (full lines);
// permute goes through a 4.3KB padded LDS tile; writes are linear 16B chunks in fragment order:
// per panel [kblk=C/32][lane=64][8 bf16], lane -> W[p*16+(lane&15)][kblk*32+(lane>>4)*8 ..+8].
#define SH_PAD 136   // bf16 row stride in LDS: 272B = 17x16 -> uint4-aligned
__global__ __launch_bounds__(256) void shuf_kernel(
    const float* __restrict__ w1, const float* __restrict__ w3, const float* __restrict__ w2,
    unsigned short* __restrict__ w1s, unsigned short* __restrict__ w3s,
    unsigned short* __restrict__ w2s)
{
  __shared__ unsigned short P[16 * SH_PAD];
  const int t = threadIdx.x;
  for (int u = blockIdx.x; u < 24576; u += gridDim.x) {
    const float* s; unsigned short* d; int C, v, logcpr;
    if (u < 8192)       { s = w1; d = w1s; C = HIDDEN;  v = u;         logcpr = 3; }
    else if (u < 16384) { s = w3; d = w3s; C = HIDDEN;  v = u - 8192;  logcpr = 3; }
    else                { s = w2; d = w2s; C = FFN_DIM; v = u - 16384; logcpr = 4; }
    const int p = v >> logcpr;
    const int c = v & ((1 << logcpr) - 1);
    const float* src = s + (size_t)p * 16 * C + c * 128;
    // load 16 rows x 128 fp32, fully coalesced (each row: 32 consecutive float4)
#pragma unroll
    for (int i = 0; i < 2; ++i) {
      int idx = t + i * 256;                 // 0..511
      int row = idx >> 5;
      int c4  = idx & 31;
      float4 vf = *(const float4*)(src + (size_t)row * C + c4 * 4);
      ushort4 o; o.x = f2bf(vf.x); o.y = f2bf(vf.y); o.z = f2bf(vf.z); o.w = f2bf(vf.w);
      *(ushort4*)(P + row * SH_PAD + c4 * 4) = o;
    }
    __syncthreads();
    // write 256 x 16B in fragment order (linear global stores)
    {
      int kl   = t >> 6;                     // local kblk 0..3
      int lane = t & 63;
      int row  = lane & 15;
      int kc   = kl * 32 + ((lane >> 4) << 3);
      uint4 val = *(const uint4*)(P + row * SH_PAD + kc);
      *(uint4*)(d + (size_t)p * 16 * C + ((size_t)(c * 4 + kl) * 64 + lane) * 8) = val;
    }
    __syncthreads();
  }
}

// ---------------- GEMM1: H = silu(X W1^T) * (X W3^T) ------------------------------------------
// M=128 x N=128, 512 thr / 8 waves (2 M-halves x 4 N-strips of 32). X via g2l LDS dbuf
// (swizzled, L2-hot -> cheap barrier; 2 calls/thread/step). B fragments DIRECT from shuffled
// global: contiguous 1KB wave-reads, per-wave counted vmcnt, never block-coupled.
// M=128 halves the B panel re-read count vs M=64 (each panel now serves 128 rows).
__global__ __launch_bounds__(512, 2) void gemm1_kernel(
    const unsigned short* __restrict__ xbf,   // [NTOK][HIDDEN] bf16
    const unsigned short* __restrict__ w1s,   // shuffled
    const unsigned short* __restrict__ w3s,
    const int* __restrict__ cnt, const int* __restrict__ base,
    const int* __restrict__ tok,
    unsigned short* __restrict__ H)           // [MAXROWS][FFN] bf16
{
  const int bid  = blockIdx.x;
  const int e    = bid & 7;                   // expert -> XCD
  const int slot = bid >> 3;                  // 0..255
  const int mt   = slot & 15;                 // 128-row token tile (mt fastest)
  const int nt   = slot >> 4;                 // 0..15, 128-col ffn tile
  const int n = cnt[e];
  if (mt * 128 >= n) return;
  const int t = threadIdx.x;
  const int w = t >> 6, l = t & 63;
  const int wm = w & 1;                       // M half (0..1)
  const int wn = w >> 1;                      // N strip (0..3)

  __shared__ unsigned short Xs[2][128 * 64];  // 2 x 16 KB

  const int sr = t >> 3;                      // staged row 0..63 (calls add 0,64)
  const int kp = ((t & 7) ^ (sr & 7)) << 3;   // pre-swizzled k-elem offset (same both calls)
  const unsigned short* xq0 = xbf + (size_t)tok[e * NTOK + min(mt * 128 + sr, n - 1)]      * HIDDEN + kp;
  const unsigned short* xq1 = xbf + (size_t)tok[e * NTOK + min(mt * 128 + 64 + sr, n - 1)] * HIDDEN + kp;

  const int lr = l & 15;
  const int lg = l >> 4;

  // B streams: wave strip wn owns panels {nt*8 + wn*2, +1}; kblk advance 512 elems
  const size_t eoff = (size_t)e * FFN_DIM * HIDDEN;
  const unsigned short* b1p[2];
  const unsigned short* b3p[2];
#pragma unroll
  for (int ni = 0; ni < 2; ++ni) {
    const size_t nblk = (size_t)(nt * 8 + wn * 2 + ni);
    b1p[ni] = w1s + eoff + nblk * (HIDDEN / 32) * 512 + l * 8;
    b3p[ni] = w3s + eoff + nblk * (HIDDEN / 32) * 512 + l * 8;
  }

  f32x4 acc1[4][2], acc3[4][2];
#pragma unroll
  for (int i = 0; i < 4; ++i)
#pragma unroll
    for (int j = 0; j < 2; ++j) { acc1[i][j] = (f32x4)0.f; acc3[i][j] = (f32x4)0.f; }

  const int Moff = wm * 64;

  // prologue: stage X(0)
  ld_g2l16(xq0, (char*)Xs[0] + w * 1024);
  ld_g2l16(xq1, (char*)Xs[0] + 8192 + w * 1024);
  __syncthreads();

  for (int kb = 0; kb < HIDDEN / 64; ++kb) {
    const int cur = kb & 1;
    if (kb + 1 < HIDDEN / 64) {               // stage X(kb+1), in flight across compute
      ld_g2l16(xq0 + (kb + 1) * 64, (char*)Xs[cur ^ 1] + w * 1024);
      ld_g2l16(xq1 + (kb + 1) * 64, (char*)Xs[cur ^ 1] + 8192 + w * 1024);
    }
    const char* Xc = (const char*)Xs[cur];
#pragma unroll
    for (int s = 0; s < 2; ++s) {             // 2 kblks per BK=64 step
      const int kblk = kb * 2 + s;
      bf16x8 b1[2], b3[2];
#pragma unroll
      for (int ni = 0; ni < 2; ++ni) {        // contiguous 1KB wave-reads
        b1[ni] = *(const bf16x8*)(b1p[ni] + (size_t)kblk * 512);
        b3[ni] = *(const bf16x8*)(b3p[ni] + (size_t)kblk * 512);
      }
      const int ub = 4 * s + lg;
      bf16x8 a[4];
#pragma unroll
      for (int mi = 0; mi < 4; ++mi) {
        const int R = Moff + mi * 16 + lr;
        a[mi] = *(const bf16x8*)(Xc + R * 128 + ((ub ^ (R & 7)) << 4));
      }
#pragma unroll
      for (int mi = 0; mi < 4; ++mi)
#pragma unroll
        for (int ni = 0; ni < 2; ++ni) {
          acc1[mi][ni] = __builtin_amdgcn_mfma_f32_16x16x32_bf16(a[mi], b1[ni], acc1[mi][ni], 0, 0, 0);
          acc3[mi][ni] = __builtin_amdgcn_mfma_f32_16x16x32_bf16(a[mi], b3[ni], acc3[mi][ni], 0, 0, 0);
        }
    }
    __syncthreads();                          // drains only this step's 2 X g2l
  }

  const size_t rbase = (size_t)base[e] + (size_t)mt * 128;
#pragma unroll
  for (int mi = 0; mi < 4; ++mi)
#pragma unroll
    for (int ni = 0; ni < 2; ++ni)
#pragma unroll
      for (int j = 0; j < 4; ++j) {
        int row = Moff + mi * 16 + lg * 4 + j;
        int col = nt * 128 + wn * 32 + ni * 16 + lr;
        float s1 = acc1[mi][ni][j], s3 = acc3[mi][ni][j];
        float h = (s1 / (1.f + __expf(-s1))) * s3;      // silu(s1)*s3
        H[(rbase + row) * FFN_DIM + col] = f2bf(h);
      }
}

// ---------------- GEMM2: Y = H W2^T, M=128 x N=128, split-K x2, same structure ----------------
__global__ __launch_bounds__(512, 2) void gemm2_kernel(
    const unsigned short* __restrict__ H,
    const unsigned short* __restrict__ w2s,   // shuffled
    const int* __restrict__ cnt, const int* __restrict__ base,
    const int* __restrict__ tok, const float* __restrict__ wgt,
    float* __restrict__ out)
{
  const int bid  = blockIdx.x;
  const int e    = bid & 7;
  const int slot = bid >> 3;                  // 0..255
  const int mt   = slot & 15;                 // 128-row token tile
  const int nt   = (slot >> 4) & 7;           // 128-col hidden tile
  const int sk   = slot >> 7;                 // split-K 0..1
  const int n = cnt[e];
  if (mt * 128 >= n) return;
  const int t = threadIdx.x;
  const int w = t >> 6, l = t & 63;
  const int wm = w & 1;
  const int wn = w >> 1;

  __shared__ unsigned short Hs[2][128 * 64];  // 2 x 16 KB
  __shared__ int   stok[128];
  __shared__ float swgt[128];

  if (t < 128) {
    int idx = mt * 128 + t;
    int ok = idx < n;
    stok[t] = ok ? tok[e * NTOK + idx] : -1;
    swgt[t] = ok ? wgt[e * NTOK + idx] : 0.f;
  }

  const int sr = t >> 3;
  const int kp = ((t & 7) ^ (sr & 7)) << 3;
  const unsigned short* hq0 = H + (size_t)(base[e] + mt * 128 + sr)      * FFN_DIM + sk * (FFN_DIM / 2) + kp;
  const unsigned short* hq1 = H + (size_t)(base[e] + mt * 128 + 64 + sr) * FFN_DIM + sk * (FFN_DIM / 2) + kp;

  const int lr = l & 15;
  const int lg = l >> 4;

  const unsigned short* b2p[2];
#pragma unroll
  for (int ni = 0; ni < 2; ++ni) {
    const size_t nblk = (size_t)(nt * 8 + wn * 2 + ni);
    b2p[ni] = w2s + (size_t)e * HIDDEN * FFN_DIM
                  + (nblk * (FFN_DIM / 32) + (size_t)sk * 32) * 512 + l * 8;
  }

  f32x4 acc[4][2];
#pragma unroll
  for (int i = 0; i < 4; ++i)
#pragma unroll
    for (int j = 0; j < 2; ++j) acc[i][j] = (f32x4)0.f;

  const int Moff = wm * 64;

  ld_g2l16(hq0, (char*)Hs[0] + w * 1024);
  ld_g2l16(hq1, (char*)Hs[0] + 8192 + w * 1024);
  __syncthreads();

  const int NK = FFN_DIM / 2 / 64;            // 16 steps
  for (int kb = 0; kb < NK; ++kb) {
    const int cur = kb & 1;
    if (kb + 1 < NK) {
      ld_g2l16(hq0 + (kb + 1) * 64, (char*)Hs[cur ^ 1] + w * 1024);
      ld_g2l16(hq1 + (kb + 1) * 64, (char*)Hs[cur ^ 1] + 8192 + w * 1024);
    }
    const char* Hc = (const char*)Hs[cur];
#pragma unroll
    for (int s = 0; s < 2; ++s) {
      const int kblk = kb * 2 + s;
      bf16x8 b[2];
#pragma unroll
      for (int ni = 0; ni < 2; ++ni)
        b[ni] = *(const bf16x8*)(b2p[ni] + (size_t)kblk * 512);
      const int ub = 4 * s + lg;
      bf16x8 a[4];
#pragma unroll
      for (int mi = 0; mi < 4; ++mi) {
        const int R = Moff + mi * 16 + lr;
        a[mi] = *(const bf16x8*)(Hc + R * 128 + ((ub ^ (R & 7)) << 4));
      }
#pragma unroll
      for (int mi = 0; mi < 4; ++mi)
#pragma unroll
        for (int ni = 0; ni < 2; ++ni)
          acc[mi][ni] = __builtin_amdgcn_mfma_f32_16x16x32_bf16(a[mi], b[ni], acc[mi][ni], 0, 0, 0);
    }
    __syncthreads();
  }

#pragma unroll
  for (int mi = 0; mi < 4; ++mi)
#pragma unroll
    for (int ni = 0; ni < 2; ++ni)
#pragma unroll
      for (int j = 0; j < 4; ++j) {
        int row = Moff + mi * 16 + lg * 4 + j;
        int tk = stok[row];
        if (tk >= 0) {
          int col = nt * 128 + wn * 32 + ni * 16 + lr;
          atomicAdd(&out[(size_t)tk * HIDDEN + col], swgt[row] * acc[mi][ni][j]);
        }
      }
}

// ================= fp32 fallback path (used only if ws too small) =================
#define TT 12
#define FC 256
#define NCHUNK (FFN_DIM / FC)

__global__ __launch_bounds__(256) void moe_ffn_kernel(
    const float* __restrict__ x,
    const float* __restrict__ w1, const float* __restrict__ w2,
    const float* __restrict__ w3,
    const int* __restrict__ cnt, const int* __restrict__ tok,
    const float* __restrict__ wgt, float* __restrict__ out)
{
  const int e  = blockIdx.y;
  const int n  = cnt[e];
  const int ts = blockIdx.x * TT;
  if (ts >= n) return;
  const int tid = threadIdx.x;

  __shared__ float xs[TT * HIDDEN];
  __shared__ float hc[TT * FC];
  __shared__ int   stok[TT];
  __shared__ float swgt[TT];

  if (tid < TT) {
    int idx = ts + tid;
    int tk  = (idx < n) ? tok[e * NTOK + idx] : -1;
    stok[tid] = tk;
    swgt[tid] = (idx < n) ? wgt[e * NTOK + idx] : 0.f;
  }
  __syncthreads();
#pragma unroll
  for (int i = 0; i < TT; ++i) {
    int tk = stok[i];
    float4 v = make_float4(0.f, 0.f, 0.f, 0.f);
    if (tk >= 0) v = ((const float4*)(x + (size_t)tk * HIDDEN))[tid];
    ((float4*)(xs + i * HIDDEN))[tid] = v;
  }
  __syncthreads();

  const float* w1e = w1 + (size_t)e * FFN_DIM * HIDDEN;
  const float* w3e = w3 + (size_t)e * FFN_DIM * HIDDEN;
  const float* w2e = w2 + (size_t)e * HIDDEN * FFN_DIM;

  float yacc[4][TT];
#pragma unroll
  for (int j = 0; j < 4; ++j)
#pragma unroll
    for (int t = 0; t < TT; ++t) yacc[j][t] = 0.f;

  for (int c = 0; c < NCHUNK; ++c) {
    const int f = c * FC + tid;
    const float4* r1 = (const float4*)(w1e + (size_t)f * HIDDEN);
    const float4* r3 = (const float4*)(w3e + (size_t)f * HIDDEN);
    float a1[TT], a3[TT];
#pragma unroll
    for (int t = 0; t < TT; ++t) { a1[t] = 0.f; a3[t] = 0.f; }
    for (int k = 0; k < HIDDEN / 4; ++k) {
      float4 v1 = r1[k];
      float4 v3 = r3[k];
#pragma unroll
      for (int t = 0; t < TT; ++t) {
        float4 xv = *(const float4*)(xs + t * HIDDEN + 4 * k);
        a1[t] += xv.x * v1.x + xv.y * v1.y + xv.z * v1.z + xv.w * v1.w;
        a3[t] += xv.x * v3.x + xv.y * v3.y + xv.z * v3.z + xv.w * v3.w;
      }
    }
    __syncthreads();
#pragma unroll
    for (int t = 0; t < TT; ++t) {
      float g  = a1[t];
      float sg = g / (1.f + __expf(-g));
      hc[t * FC + tid] = sg * a3[t];
    }
    __syncthreads();
    const float4* r20 = (const float4*)(w2e + (size_t)(tid      ) * FFN_DIM + c * FC);
    const float4* r21 = (const float4*)(w2e + (size_t)(tid + 256) * FFN_DIM + c * FC);
    const float4* r22 = (const float4*)(w2e + (size_t)(tid + 512) * FFN_DIM + c * FC);
    const float4* r23 = (const float4*)(w2e + (size_t)(tid + 768) * FFN_DIM + c * FC);
    for (int k = 0; k < FC / 4; ++k) {
      float4 wv0 = r20[k], wv1 = r21[k], wv2 = r22[k], wv3 = r23[k];
#pragma unroll
      for (int t = 0; t < TT; ++t) {
        float4 hv = *(const float4*)(hc + t * FC + 4 * k);
        yacc[0][t] += hv.x * wv0.x + hv.y * wv0.y + hv.z * wv0.z + hv.w * wv0.w;
        yacc[1][t] += hv.x * wv1.x + hv.y * wv1.y + hv.z * wv1.z + hv.w * wv1.w;
        yacc[2][t] += hv.x * wv2.x + hv.y * wv2.y + hv.z * wv2.z + hv.w * wv2.w;
        yacc[3][t] += hv.x * wv3.x + hv.y * wv3.y + hv.z * wv3.z + hv.w * wv3.w;
      }
    }
  }

#pragma unroll
  for (int t = 0; t < TT; ++t) {
    int tk = stok[t];
    if (tk < 0) continue;
    float wt = swgt[t];
    float* orow = out + (size_t)tk * HIDDEN;
    atomicAdd(orow + tid,       wt * yacc[0][t]);
    atomicAdd(orow + tid + 256, wt * yacc[1][t]);
    atomicAdd(orow + tid + 512, wt * yacc[2][t]);
    atomicAdd(orow + tid + 768, wt * yacc[3][t]);
  }
}

extern "C" void kernel_launch(void* const* d_in, const int* in_sizes, int n_in,
                              void* d_out, int out_size, void* d_ws, size_t ws_size,
                              hipStream_t stream) {
  const float* x  = (const float*)d_in[0];
  const float* gw = (const float*)d_in[1];
  const float* w1 = (const float*)d_in[2];
  const float* w2 = (const float*)d_in[3];
  const float* w3 = (const float*)d_in[4];
  float* out    = (float*)d_out;
  float* logits = out + (size_t)NTOK * HIDDEN;

  char* ws = (char*)d_ws;
  int*   cnt  = (int*)(ws + OFF_CNT);
  int*   base = (int*)(ws + OFF_BASE);
  int*   tokp = (int*)(ws + OFF_TOK);
  float* wgtp = (float*)(ws + OFF_WGT);

  const bool big = (ws_size >= WS_NEED);
  unsigned short* xbf  = big ? (unsigned short*)(ws + OFF_XBF) : (unsigned short*)0;
  unsigned short* w1sh = big ? (unsigned short*)(ws + OFF_W1S) : (unsigned short*)0;
  unsigned short* w3sh = big ? (unsigned short*)(ws + OFF_W3S) : (unsigned short*)0;
  unsigned short* w2sh = big ? (unsigned short*)(ws + OFF_W2S) : (unsigned short*)0;
  unsigned short* Hbuf = big ? (unsigned short*)(ws + OFF_H)   : (unsigned short*)0;

  hipMemsetAsync(out, 0, (size_t)NTOK * HIDDEN * sizeof(float), stream);
  hipMemsetAsync(cnt, 0, NEXP * sizeof(int), stream);

  router_kernel<<<NTOK, 256, 0, stream>>>(x, gw, logits, cnt, tokp, wgtp, xbf);

  if (big) {
    shuf_kernel<<<4096, 256, 0, stream>>>(w1, w3, w2, w1sh, w3sh, w2sh);
    prefix_kernel<<<1, 64, 0, stream>>>(cnt, base);

    gemm1_kernel<<<NEXP * 16 * 16, 512, 0, stream>>>(xbf, w1sh, w3sh, cnt, base, tokp, Hbuf);
    gemm2_kernel<<<NEXP * 16 * 8 * 2, 512, 0, stream>>>(Hbuf, w2sh, cnt, base, tokp, wgtp, out);
  } else {
    dim3 grid((NTOK + TT - 1) / TT, NEXP);
    moe_ffn_kernel<<<grid, 256, 0, stream>>>(x, w1, w2, w3, cnt, tokp, wgtp, out);
  }
}